// Round 1
// baseline (1805.535 us; speedup 1.0000x reference)
//
#include <hip/hip_runtime.h>

// GATConv forward, fp32, MI355X.
// N=100000 nodes, E=1600000 edges, IN_F=128, HEADS=6, OUT_F=32 (HC=192).
// Pipeline: memset -> k_gemm (xp, a_s, a_d) -> k_deg -> k_scan (CSR offsets)
//           -> k_scatter (CSR perm/src) -> k_edge (exp logits, CSR order)
//           -> k_agg (per-dst-node softmax-weighted aggregation + SELU).

#define TN 64          // nodes per gemm block
#define XS_PAD 68      // [k][n] LDS stride: k*68+8*nt is 16B aligned -> ds_read_b128
#define CAP 1024       // per-node LDS edge cache in k_agg

__global__ __launch_bounds__(256) void k_gemm(
    const float* __restrict__ x, const float* __restrict__ W,
    const float* __restrict__ att_src, const float* __restrict__ att_dst,
    float* __restrict__ xp, float* __restrict__ a_s, float* __restrict__ a_d,
    int N)
{
    __shared__ float xs[128 * XS_PAD];
    const int t  = threadIdx.x;
    const int n0 = blockIdx.x * TN;

    // Stage x tile transposed: xs[k][n]. Global read coalesced over k.
    for (int i = t; i < TN * 128; i += 256) {
        int n = i >> 7, k = i & 127;
        int gn = n0 + n;
        float v = 0.f;
        if (gn < N) v = x[gn * 128 + k];
        xs[k * XS_PAD + n] = v;
    }
    __syncthreads();

    const int ct = t & 31;   // column within head (c)
    const int nt = t >> 5;   // node-octet id (0..7)

    float acc[8][6];
    #pragma unroll
    for (int i = 0; i < 8; ++i)
        #pragma unroll
        for (int j = 0; j < 6; ++j) acc[i][j] = 0.f;

    const float* Wp = W + ct;
    for (int k = 0; k < 128; ++k) {
        float w[6];
        #pragma unroll
        for (int j = 0; j < 6; ++j) w[j] = Wp[k * 192 + 32 * j];
        const float4* xr = (const float4*)(xs + k * XS_PAD + nt * 8);
        float4 xa = xr[0];
        float4 xb = xr[1];
        float xv[8] = {xa.x, xa.y, xa.z, xa.w, xb.x, xb.y, xb.z, xb.w};
        #pragma unroll
        for (int i = 0; i < 8; ++i)
            #pragma unroll
            for (int j = 0; j < 6; ++j) acc[i][j] += xv[i] * w[j];
    }

    // Store xp (coalesced over ct).
    #pragma unroll
    for (int i = 0; i < 8; ++i) {
        int gn = n0 + nt * 8 + i;
        if (gn < N) {
            #pragma unroll
            for (int j = 0; j < 6; ++j)
                xp[(size_t)gn * 192 + 32 * j + ct] = acc[i][j];
        }
    }

    // Fused attention halves: a_s[n][h] = sum_c xp[n][h][c]*att_src[h][c].
    // col = 32*j + ct  =>  h == j, c == ct: reduce over the 32 ct-lanes.
    float asc[6], adc[6];
    #pragma unroll
    for (int j = 0; j < 6; ++j) {
        asc[j] = att_src[j * 32 + ct];
        adc[j] = att_dst[j * 32 + ct];
    }
    #pragma unroll
    for (int i = 0; i < 8; ++i) {
        int gn = n0 + nt * 8 + i;
        #pragma unroll
        for (int j = 0; j < 6; ++j) {
            float vs = acc[i][j] * asc[j];
            float vd = acc[i][j] * adc[j];
            #pragma unroll
            for (int d = 16; d; d >>= 1) {
                vs += __shfl_down(vs, d, 32);
                vd += __shfl_down(vd, d, 32);
            }
            if (ct == 0 && gn < N) {
                a_s[gn * 6 + j] = vs;
                a_d[gn * 6 + j] = vd;
            }
        }
    }
}

__global__ void k_deg(const int* __restrict__ ei, int* __restrict__ deg, int E)
{
    int e = blockIdx.x * blockDim.x + threadIdx.x;
    if (e < E) atomicAdd(&deg[ei[E + e]], 1);
}

__global__ __launch_bounds__(1024) void k_scan(
    const int* __restrict__ deg, int* __restrict__ off, int N)
{
    __shared__ int sd[1024];
    const int t = threadIdx.x;
    const int chunk = (N + 1023) >> 10;
    int start = t * chunk;
    int end   = start + chunk; if (end > N) end = N;
    int sum = 0;
    for (int i = start; i < end; ++i) sum += deg[i];
    sd[t] = sum;
    __syncthreads();
    for (int o = 1; o < 1024; o <<= 1) {
        int v = sd[t];
        int add = (t >= o) ? sd[t - o] : 0;
        __syncthreads();
        sd[t] = v + add;
        __syncthreads();
    }
    int run = sd[t] - sum;   // exclusive base for this chunk
    for (int i = start; i < end; ++i) { off[i] = run; run += deg[i]; }
    if (t == 1023) off[N] = sd[1023];
}

__global__ void k_scatter(const int* __restrict__ ei, const int* __restrict__ off,
                          int* __restrict__ cursor, int* __restrict__ perm,
                          int* __restrict__ csr_src, int E)
{
    int e = blockIdx.x * blockDim.x + threadIdx.x;
    if (e < E) {
        int dst = ei[E + e];
        int p = off[dst] + atomicAdd(&cursor[dst], 1);
        perm[e] = p;
        csr_src[p] = ei[e];
    }
}

__global__ void k_edge(const int* __restrict__ ei, const int* __restrict__ perm,
                       const float* __restrict__ a_s, const float* __restrict__ a_d,
                       float* __restrict__ exs, int E)
{
    int e = blockIdx.x * blockDim.x + threadIdx.x;
    if (e >= E) return;
    int src = ei[e];
    int dst = ei[E + e];
    int p = perm[e];
    const float2* sp = (const float2*)(a_s + (size_t)src * 6);
    const float2* dp = (const float2*)(a_d + (size_t)dst * 6);
    float2 s01 = sp[0], s23 = sp[1], s45 = sp[2];
    float2 d01 = dp[0], d23 = dp[1], d45 = dp[2];
    float z[6] = {s01.x + d01.x, s01.y + d01.y, s23.x + d23.x,
                  s23.y + d23.y, s45.x + d45.x, s45.y + d45.y};
    float ex[6];
    #pragma unroll
    for (int j = 0; j < 6; ++j) {
        float v = z[j];
        v = v > 0.f ? v : 0.2f * v;     // LeakyReLU
        ex[j] = __expf(v);              // no max-subtraction: logits are tiny
    }
    float2* op = (float2*)(exs + (size_t)p * 6);
    op[0] = make_float2(ex[0], ex[1]);
    op[1] = make_float2(ex[2], ex[3]);
    op[2] = make_float2(ex[4], ex[5]);
}

__global__ __launch_bounds__(192) void k_agg(
    const float* __restrict__ xp, const float* __restrict__ exs,
    const int* __restrict__ csr_src, const int* __restrict__ off,
    const float* __restrict__ bias, float* __restrict__ out, int N)
{
    __shared__ int   s_src[CAP];
    __shared__ float s_ex[CAP * 6];
    __shared__ float s_sum[6];
    __shared__ float s_red[192];

    const int n = blockIdx.x;
    const int t = threadIdx.x;
    const int h = t >> 5, cc = t & 31;

    const int nb = off[n], ne = off[n + 1];
    const int deg = ne - nb;
    const bool fits = (deg <= CAP);

    if (t < 6) s_sum[t] = 0.f;
    __syncthreads();

    float part[6] = {0.f, 0.f, 0.f, 0.f, 0.f, 0.f};
    for (int i = t; i < deg; i += 192) {
        int gs = csr_src[nb + i];
        const float2* ep = (const float2*)(exs + (size_t)(nb + i) * 6);
        float2 e01 = ep[0], e23 = ep[1], e45 = ep[2];
        part[0] += e01.x; part[1] += e01.y;
        part[2] += e23.x; part[3] += e23.y;
        part[4] += e45.x; part[5] += e45.y;
        if (fits) {
            s_src[i] = gs;
            float2* q = (float2*)(s_ex + i * 6);
            q[0] = e01; q[1] = e23; q[2] = e45;
        }
    }
    #pragma unroll
    for (int j = 0; j < 6; ++j) atomicAdd(&s_sum[j], part[j]);
    __syncthreads();

    const float inv_s = 1.f / (s_sum[h] + 1e-16f);

    float acc = 0.f;
    if (fits) {
        for (int i = 0; i < deg; ++i) {
            int gs = s_src[i];
            float ev = s_ex[i * 6 + h];
            acc += ev * xp[(size_t)gs * 192 + t];
        }
    } else {
        for (int i = 0; i < deg; ++i) {
            int gs = csr_src[nb + i];
            float ev = exs[(size_t)(nb + i) * 6 + h];
            acc += ev * xp[(size_t)gs * 192 + t];
        }
    }

    s_red[t] = acc * inv_s;
    __syncthreads();

    if (t < 32) {
        float r = 0.f;
        #pragma unroll
        for (int j = 0; j < 6; ++j) r += s_red[j * 32 + t];
        float v = r * (1.f / 6.f) + bias[t];
        const float sc = 1.0507009873554805f, al = 1.6732632423543772f;
        v = v > 0.f ? sc * v : sc * al * (__expf(v) - 1.f);
        out[(size_t)n * 32 + t] = v;
    }
    (void)cc;
}

extern "C" void kernel_launch(void* const* d_in, const int* in_sizes, int n_in,
                              void* d_out, int out_size, void* d_ws, size_t ws_size,
                              hipStream_t stream)
{
    const float* x       = (const float*)d_in[0];
    const int*   ei      = (const int*)d_in[1];   // [2][E] int32 (JAX x64 off)
    const float* W       = (const float*)d_in[2];
    const float* att_src = (const float*)d_in[3];
    const float* att_dst = (const float*)d_in[4];
    const float* bias    = (const float*)d_in[5];
    float* out = (float*)d_out;

    const int N = in_sizes[0] / 128;
    const int E = in_sizes[1] / 2;

    char* ws = (char*)d_ws;
    size_t o = 0;
    auto take = [&](size_t bytes) { size_t r = o; o = (o + bytes + 255) & ~(size_t)255; return r; };
    float* xp      = (float*)(ws + take((size_t)N * 192 * 4));
    float* a_s     = (float*)(ws + take((size_t)N * 6 * 4));
    float* a_d     = (float*)(ws + take((size_t)N * 6 * 4));
    float* exs     = (float*)(ws + take((size_t)E * 6 * 4));
    int*   off     = (int*)  (ws + take((size_t)(N + 1) * 4));
    int*   degcur  = (int*)  (ws + take((size_t)2 * N * 4));  // deg | cursor
    int*   deg     = degcur;
    int*   cursor  = degcur + N;
    int*   perm    = (int*)  (ws + take((size_t)E * 4));
    int*   csr_src = (int*)  (ws + take((size_t)E * 4));
    (void)ws_size; (void)n_in; (void)out_size;

    hipMemsetAsync(degcur, 0, (size_t)2 * N * 4, stream);

    k_gemm<<<(N + TN - 1) / TN, 256, 0, stream>>>(x, W, att_src, att_dst,
                                                  xp, a_s, a_d, N);
    int eg = (E + 255) / 256;
    k_deg<<<eg, 256, 0, stream>>>(ei, deg, E);
    k_scan<<<1, 1024, 0, stream>>>(deg, off, N);
    k_scatter<<<eg, 256, 0, stream>>>(ei, off, cursor, perm, csr_src, E);
    k_edge<<<eg, 256, 0, stream>>>(ei, perm, a_s, a_d, exs, E);
    k_agg<<<N, 192, 0, stream>>>(xp, exs, csr_src, off, bias, out, N);
}

// Round 2
// 735.171 us; speedup vs baseline: 2.4559x; 2.4559x over previous
//
#include <hip/hip_runtime.h>

// GATConv forward, fp32, MI355X.
// N=100000 nodes, E=1600000 edges, IN_F=128, HEADS=6, OUT_F=32 (HC=192).
// Pipeline: memset -> k_gemm (xp, a_s, a_d) -> k_deg -> k_scan (CSR offsets)
//           -> k_scatedge (CSR scatter + exp logits fused)
//           -> k_agg (wave-per-node softmax-weighted aggregation + SELU).
//
// R2 change: k_agg rewritten wave-per-node (was block-per-node + LDS cache).
//   - no LDS -> occupancy no longer LDS-capped (was 29KB/block, 44%)
//   - src indices preloaded 1/lane + __shfl broadcast -> no load->load chain
//   - 8x unrolled gather -> 8 outstanding global_load_dwordx4 per lane
//   - softmax denom fused into the same pass (scale after loop)
// k_edge folded into k_scatter (perm array eliminated).

#define TN 64          // nodes per gemm block
#define XS_PAD 68      // [k][n] LDS stride: k*68+8*nt is 16B aligned -> ds_read_b128

__global__ __launch_bounds__(256) void k_gemm(
    const float* __restrict__ x, const float* __restrict__ W,
    const float* __restrict__ att_src, const float* __restrict__ att_dst,
    float* __restrict__ xp, float* __restrict__ a_s, float* __restrict__ a_d,
    int N)
{
    __shared__ float xs[128 * XS_PAD];
    const int t  = threadIdx.x;
    const int n0 = blockIdx.x * TN;

    for (int i = t; i < TN * 128; i += 256) {
        int n = i >> 7, k = i & 127;
        int gn = n0 + n;
        float v = 0.f;
        if (gn < N) v = x[gn * 128 + k];
        xs[k * XS_PAD + n] = v;
    }
    __syncthreads();

    const int ct = t & 31;   // column within head (c)
    const int nt = t >> 5;   // node-octet id (0..7)

    float acc[8][6];
    #pragma unroll
    for (int i = 0; i < 8; ++i)
        #pragma unroll
        for (int j = 0; j < 6; ++j) acc[i][j] = 0.f;

    const float* Wp = W + ct;
    for (int k = 0; k < 128; ++k) {
        float w[6];
        #pragma unroll
        for (int j = 0; j < 6; ++j) w[j] = Wp[k * 192 + 32 * j];
        const float4* xr = (const float4*)(xs + k * XS_PAD + nt * 8);
        float4 xa = xr[0];
        float4 xb = xr[1];
        float xv[8] = {xa.x, xa.y, xa.z, xa.w, xb.x, xb.y, xb.z, xb.w};
        #pragma unroll
        for (int i = 0; i < 8; ++i)
            #pragma unroll
            for (int j = 0; j < 6; ++j) acc[i][j] += xv[i] * w[j];
    }

    #pragma unroll
    for (int i = 0; i < 8; ++i) {
        int gn = n0 + nt * 8 + i;
        if (gn < N) {
            #pragma unroll
            for (int j = 0; j < 6; ++j)
                xp[(size_t)gn * 192 + 32 * j + ct] = acc[i][j];
        }
    }

    float asc[6], adc[6];
    #pragma unroll
    for (int j = 0; j < 6; ++j) {
        asc[j] = att_src[j * 32 + ct];
        adc[j] = att_dst[j * 32 + ct];
    }
    #pragma unroll
    for (int i = 0; i < 8; ++i) {
        int gn = n0 + nt * 8 + i;
        #pragma unroll
        for (int j = 0; j < 6; ++j) {
            float vs = acc[i][j] * asc[j];
            float vd = acc[i][j] * adc[j];
            #pragma unroll
            for (int d = 16; d; d >>= 1) {
                vs += __shfl_down(vs, d, 32);
                vd += __shfl_down(vd, d, 32);
            }
            if (ct == 0 && gn < N) {
                a_s[gn * 6 + j] = vs;
                a_d[gn * 6 + j] = vd;
            }
        }
    }
}

__global__ void k_deg(const int* __restrict__ ei, int* __restrict__ deg, int E)
{
    int e = blockIdx.x * blockDim.x + threadIdx.x;
    if (e < E) atomicAdd(&deg[ei[E + e]], 1);
}

__global__ __launch_bounds__(1024) void k_scan(
    const int* __restrict__ deg, int* __restrict__ off, int N)
{
    __shared__ int sd[1024];
    const int t = threadIdx.x;
    const int chunk = (N + 1023) >> 10;
    int start = t * chunk;
    int end   = start + chunk; if (end > N) end = N;
    int sum = 0;
    for (int i = start; i < end; ++i) sum += deg[i];
    sd[t] = sum;
    __syncthreads();
    for (int o = 1; o < 1024; o <<= 1) {
        int v = sd[t];
        int add = (t >= o) ? sd[t - o] : 0;
        __syncthreads();
        sd[t] = v + add;
        __syncthreads();
    }
    int run = sd[t] - sum;
    for (int i = start; i < end; ++i) { off[i] = run; run += deg[i]; }
    if (t == 1023) off[N] = sd[1023];
}

// CSR scatter fused with edge logit computation: writes csr_src[p] and
// exp(leakyrelu(a_s[src]+a_d[dst])) directly in CSR order. No max-subtraction:
// logits have |z| ~ 0.5, exp is safe and softmax ratio is identical.
__global__ void k_scatedge(const int* __restrict__ ei, const int* __restrict__ off,
                           int* __restrict__ cursor,
                           const float* __restrict__ a_s, const float* __restrict__ a_d,
                           int* __restrict__ csr_src, float* __restrict__ exs, int E)
{
    int e = blockIdx.x * blockDim.x + threadIdx.x;
    if (e >= E) return;
    int src = ei[e];
    int dst = ei[E + e];
    int p = off[dst] + atomicAdd(&cursor[dst], 1);
    csr_src[p] = src;
    const float2* sp = (const float2*)(a_s + (size_t)src * 6);
    const float2* dp = (const float2*)(a_d + (size_t)dst * 6);
    float2 s01 = sp[0], s23 = sp[1], s45 = sp[2];
    float2 d01 = dp[0], d23 = dp[1], d45 = dp[2];
    float z[6] = {s01.x + d01.x, s01.y + d01.y, s23.x + d23.x,
                  s23.y + d23.y, s45.x + d45.x, s45.y + d45.y};
    float ex[6];
    #pragma unroll
    for (int j = 0; j < 6; ++j) {
        float v = z[j];
        v = v > 0.f ? v : 0.2f * v;     // LeakyReLU
        ex[j] = __expf(v);
    }
    float2* op = (float2*)(exs + (size_t)p * 6);
    op[0] = make_float2(ex[0], ex[1]);
    op[1] = make_float2(ex[2], ex[3]);
    op[2] = make_float2(ex[4], ex[5]);
}

// Wave-per-node aggregation. Lane l (0..47) owns cols [4l,4l+4) of the 192-wide
// xp row (head h = l>>3). Lanes 48..63 run with clamped addresses (their
// results are zeroed before the head-mean reduction). Single pass accumulates
// both sum(ev) and sum(ev * xp[src]); alpha scaling applied after the loop.
__global__ __launch_bounds__(256) void k_agg(
    const float* __restrict__ xp, const float* __restrict__ exs,
    const int* __restrict__ csr_src, const int* __restrict__ off,
    const float* __restrict__ bias, float* __restrict__ out, int N)
{
    const int wid = threadIdx.x >> 6;
    const int l   = threadIdx.x & 63;
    const int n = blockIdx.x * 4 + wid;
    if (n >= N) return;

    const int nb  = off[n];
    const int deg = off[n + 1] - nb;
    const int hr  = l >> 3;
    const int h   = hr < 6 ? hr : 5;      // clamp for lanes 48..63
    const int lc  = l < 48 ? l : 47;      // clamp for lanes 48..63
    const float4* __restrict__ xp4 = (const float4*)xp;

    float ax = 0.f, ay = 0.f, az = 0.f, aw = 0.f, se = 0.f;

    if (deg <= 64) {
        // Preload this node's src indices: one per lane, broadcast via shfl.
        int myidx = (l < deg) ? csr_src[nb + l] : 0;
        int i = 0;
        for (; i + 8 <= deg; i += 8) {
            int s[8]; float ev[8]; float4 xv[8];
            #pragma unroll
            for (int k = 0; k < 8; ++k) {
                s[k]  = __shfl(myidx, i + k);
                ev[k] = exs[(nb + i + k) * 6 + h];
            }
            #pragma unroll
            for (int k = 0; k < 8; ++k) xv[k] = xp4[s[k] * 48 + lc];
            #pragma unroll
            for (int k = 0; k < 8; ++k) {
                ax = fmaf(ev[k], xv[k].x, ax);
                ay = fmaf(ev[k], xv[k].y, ay);
                az = fmaf(ev[k], xv[k].z, az);
                aw = fmaf(ev[k], xv[k].w, aw);
                se += ev[k];
            }
        }
        for (; i < deg; ++i) {
            int sx   = __shfl(myidx, i);
            float ev = exs[(nb + i) * 6 + h];
            float4 xv = xp4[sx * 48 + lc];
            ax = fmaf(ev, xv.x, ax);
            ay = fmaf(ev, xv.y, ay);
            az = fmaf(ev, xv.z, az);
            aw = fmaf(ev, xv.w, aw);
            se += ev;
        }
    } else {
        // Generic path (deg > 64): direct index loads, 4x unrolled.
        int i = 0;
        for (; i + 4 <= deg; i += 4) {
            int s[4]; float ev[4]; float4 xv[4];
            #pragma unroll
            for (int k = 0; k < 4; ++k) {
                s[k]  = csr_src[nb + i + k];
                ev[k] = exs[(nb + i + k) * 6 + h];
            }
            #pragma unroll
            for (int k = 0; k < 4; ++k) xv[k] = xp4[s[k] * 48 + lc];
            #pragma unroll
            for (int k = 0; k < 4; ++k) {
                ax = fmaf(ev[k], xv[k].x, ax);
                ay = fmaf(ev[k], xv[k].y, ay);
                az = fmaf(ev[k], xv[k].z, az);
                aw = fmaf(ev[k], xv[k].w, aw);
                se += ev[k];
            }
        }
        for (; i < deg; ++i) {
            int sx   = csr_src[nb + i];
            float ev = exs[(nb + i) * 6 + h];
            float4 xv = xp4[sx * 48 + lc];
            ax = fmaf(ev, xv.x, ax);
            ay = fmaf(ev, xv.y, ay);
            az = fmaf(ev, xv.z, az);
            aw = fmaf(ev, xv.w, aw);
            se += ev;
        }
    }

    const float inv = 1.f / (se + 1e-16f);
    float v0 = (l < 48) ? ax * inv : 0.f;
    float v1 = (l < 48) ? ay * inv : 0.f;
    float v2 = (l < 48) ? az * inv : 0.f;
    float v3 = (l < 48) ? aw * inv : 0.f;

    // Head mean: sum lanes {l, l+8, ..., l+40} into lanes 0..7.
    #pragma unroll
    for (int d = 8; d <= 32; d <<= 1) {
        v0 += __shfl_down(v0, d);
        v1 += __shfl_down(v1, d);
        v2 += __shfl_down(v2, d);
        v3 += __shfl_down(v3, d);
    }

    if (l < 8) {
        float4 b4 = ((const float4*)bias)[l];
        const float sc = 1.0507009873554805f, al = 1.6732632423543772f;
        float m[4] = {v0 * (1.f / 6.f) + b4.x, v1 * (1.f / 6.f) + b4.y,
                      v2 * (1.f / 6.f) + b4.z, v3 * (1.f / 6.f) + b4.w};
        #pragma unroll
        for (int k = 0; k < 4; ++k)
            m[k] = m[k] > 0.f ? sc * m[k] : sc * al * (__expf(m[k]) - 1.f);
        ((float4*)out)[(size_t)n * 8 + l] = make_float4(m[0], m[1], m[2], m[3]);
    }
}

extern "C" void kernel_launch(void* const* d_in, const int* in_sizes, int n_in,
                              void* d_out, int out_size, void* d_ws, size_t ws_size,
                              hipStream_t stream)
{
    const float* x       = (const float*)d_in[0];
    const int*   ei      = (const int*)d_in[1];   // [2][E] int32
    const float* W       = (const float*)d_in[2];
    const float* att_src = (const float*)d_in[3];
    const float* att_dst = (const float*)d_in[4];
    const float* bias    = (const float*)d_in[5];
    float* out = (float*)d_out;

    const int N = in_sizes[0] / 128;
    const int E = in_sizes[1] / 2;

    char* ws = (char*)d_ws;
    size_t o = 0;
    auto take = [&](size_t bytes) { size_t r = o; o = (o + bytes + 255) & ~(size_t)255; return r; };
    float* xp      = (float*)(ws + take((size_t)N * 192 * 4));
    float* a_s     = (float*)(ws + take((size_t)N * 6 * 4));
    float* a_d     = (float*)(ws + take((size_t)N * 6 * 4));
    float* exs     = (float*)(ws + take((size_t)E * 6 * 4));
    int*   off     = (int*)  (ws + take((size_t)(N + 1) * 4));
    int*   degcur  = (int*)  (ws + take((size_t)2 * N * 4));  // deg | cursor
    int*   deg     = degcur;
    int*   cursor  = degcur + N;
    int*   csr_src = (int*)  (ws + take((size_t)E * 4));
    (void)ws_size; (void)n_in; (void)out_size;

    hipMemsetAsync(degcur, 0, (size_t)2 * N * 4, stream);

    k_gemm<<<(N + TN - 1) / TN, 256, 0, stream>>>(x, W, att_src, att_dst,
                                                  xp, a_s, a_d, N);
    int eg = (E + 255) / 256;
    k_deg<<<eg, 256, 0, stream>>>(ei, deg, E);
    k_scan<<<1, 1024, 0, stream>>>(deg, off, N);
    k_scatedge<<<eg, 256, 0, stream>>>(ei, off, cursor, a_s, a_d, csr_src, exs, E);
    k_agg<<<(N + 3) / 4, 256, 0, stream>>>(xp, exs, csr_src, off, bias, out, N);
}

// Round 3
// 549.388 us; speedup vs baseline: 3.2864x; 1.3382x over previous
//
#include <hip/hip_runtime.h>

// GATConv forward, fp32, MI355X.
// N=100000 nodes, E=1600000 edges, IN_F=128, HEADS=6, OUT_F=32 (HC=192).
// Pipeline: memset -> k_gemm (xp, a_s, a_d) -> k_deg
//           -> k_bsum/k_bscan/k_off (hierarchical CSR offset scan)
//           -> k_scat (CSR src scatter only)
//           -> k_agg (wave-per-node: recompute exp-logits in-register,
//                     softmax-weighted aggregation + head-mean + SELU).
//
// R3 changes vs R2:
//   - exs stream eliminated: k_agg recomputes exp(leakyrelu(a_s[src]+a_d[dst]))
//     from the L2-resident a_s/a_d arrays (a_d is wave-uniform, a_s is a 4B
//     gather shared by the 8 lanes of each head). Removes 45MB scattered write
//     + 45MB read and shrinks the scatter kernel to csr_src only.
//   - single-block serial k_scan replaced by 3-kernel hierarchical scan.

#define TN 64          // nodes per gemm block
#define XS_PAD 68      // [k][n] LDS stride: k*68+8*nt is 16B aligned -> ds_read_b128

__global__ __launch_bounds__(256) void k_gemm(
    const float* __restrict__ x, const float* __restrict__ W,
    const float* __restrict__ att_src, const float* __restrict__ att_dst,
    float* __restrict__ xp, float* __restrict__ a_s, float* __restrict__ a_d,
    int N)
{
    __shared__ float xs[128 * XS_PAD];
    const int t  = threadIdx.x;
    const int n0 = blockIdx.x * TN;

    for (int i = t; i < TN * 128; i += 256) {
        int n = i >> 7, k = i & 127;
        int gn = n0 + n;
        float v = 0.f;
        if (gn < N) v = x[gn * 128 + k];
        xs[k * XS_PAD + n] = v;
    }
    __syncthreads();

    const int ct = t & 31;   // column within head (c)
    const int nt = t >> 5;   // node-octet id (0..7)

    float acc[8][6];
    #pragma unroll
    for (int i = 0; i < 8; ++i)
        #pragma unroll
        for (int j = 0; j < 6; ++j) acc[i][j] = 0.f;

    const float* Wp = W + ct;
    for (int k = 0; k < 128; ++k) {
        float w[6];
        #pragma unroll
        for (int j = 0; j < 6; ++j) w[j] = Wp[k * 192 + 32 * j];
        const float4* xr = (const float4*)(xs + k * XS_PAD + nt * 8);
        float4 xa = xr[0];
        float4 xb = xr[1];
        float xv[8] = {xa.x, xa.y, xa.z, xa.w, xb.x, xb.y, xb.z, xb.w};
        #pragma unroll
        for (int i = 0; i < 8; ++i)
            #pragma unroll
            for (int j = 0; j < 6; ++j) acc[i][j] += xv[i] * w[j];
    }

    #pragma unroll
    for (int i = 0; i < 8; ++i) {
        int gn = n0 + nt * 8 + i;
        if (gn < N) {
            #pragma unroll
            for (int j = 0; j < 6; ++j)
                xp[(size_t)gn * 192 + 32 * j + ct] = acc[i][j];
        }
    }

    float asc[6], adc[6];
    #pragma unroll
    for (int j = 0; j < 6; ++j) {
        asc[j] = att_src[j * 32 + ct];
        adc[j] = att_dst[j * 32 + ct];
    }
    #pragma unroll
    for (int i = 0; i < 8; ++i) {
        int gn = n0 + nt * 8 + i;
        #pragma unroll
        for (int j = 0; j < 6; ++j) {
            float vs = acc[i][j] * asc[j];
            float vd = acc[i][j] * adc[j];
            #pragma unroll
            for (int d = 16; d; d >>= 1) {
                vs += __shfl_down(vs, d, 32);
                vd += __shfl_down(vd, d, 32);
            }
            if (ct == 0 && gn < N) {
                a_s[gn * 6 + j] = vs;
                a_d[gn * 6 + j] = vd;
            }
        }
    }
}

__global__ void k_deg(const int* __restrict__ ei, int* __restrict__ deg, int E)
{
    int e = blockIdx.x * blockDim.x + threadIdx.x;
    if (e < E) atomicAdd(&deg[ei[E + e]], 1);
}

// ---- hierarchical exclusive scan over deg[N] -> off[N+1] ----
__global__ __launch_bounds__(256) void k_bsum(
    const int* __restrict__ deg, int* __restrict__ bsum, int N)
{
    __shared__ int sd[256];
    const int b = blockIdx.x, t = threadIdx.x;
    const int base = b * 1024;
    int s = 0;
    #pragma unroll
    for (int k = 0; k < 4; ++k) {
        int g = base + t + k * 256;
        if (g < N) s += deg[g];
    }
    sd[t] = s;
    __syncthreads();
    for (int o = 128; o; o >>= 1) {
        if (t < o) sd[t] += sd[t + o];
        __syncthreads();
    }
    if (t == 0) bsum[b] = sd[0];
}

__global__ __launch_bounds__(128) void k_bscan(
    const int* __restrict__ bsum, int* __restrict__ bbase,
    int NB, int* __restrict__ offN)
{
    __shared__ int sd[128];
    const int t = threadIdx.x;
    int v = (t < NB) ? bsum[t] : 0;
    sd[t] = v;
    __syncthreads();
    for (int o = 1; o < 128; o <<= 1) {
        int add = (t >= o) ? sd[t - o] : 0;
        __syncthreads();
        sd[t] += add;
        __syncthreads();
    }
    if (t < NB) bbase[t] = sd[t] - v;   // exclusive block base
    if (t == 127) *offN = sd[127];      // grand total -> off[N]
}

__global__ __launch_bounds__(256) void k_off(
    const int* __restrict__ deg, const int* __restrict__ bbase,
    int* __restrict__ off, int N)
{
    __shared__ int sw[256];
    const int b = blockIdx.x, t = threadIdx.x;
    const int base = b * 1024 + t * 4;
    int d[4]; int s = 0;
    #pragma unroll
    for (int k = 0; k < 4; ++k) {
        int g = base + k;
        d[k] = (g < N) ? deg[g] : 0;
        s += d[k];
    }
    sw[t] = s;
    __syncthreads();
    for (int o = 1; o < 256; o <<= 1) {
        int add = (t >= o) ? sw[t - o] : 0;
        __syncthreads();
        sw[t] += add;
        __syncthreads();
    }
    int run = bbase[b] + (sw[t] - s);   // exclusive base for this thread
    #pragma unroll
    for (int k = 0; k < 4; ++k) {
        int g = base + k;
        if (g < N) off[g] = run;
        run += d[k];
    }
}

// CSR scatter: csr_src[p] = src for edges grouped by dst.
__global__ void k_scat(const int* __restrict__ ei, const int* __restrict__ off,
                       int* __restrict__ cursor, int* __restrict__ csr_src, int E)
{
    int e = blockIdx.x * blockDim.x + threadIdx.x;
    if (e < E) {
        int dst = ei[E + e];
        int p = off[dst] + atomicAdd(&cursor[dst], 1);
        csr_src[p] = ei[e];
    }
}

// Wave-per-node aggregation. Lane l (0..47) owns cols [4l,4l+4) of the 192-wide
// xp row (head h = l>>3). Edge logits recomputed in-register:
// ev = exp(leakyrelu(a_s[src][h] + a_d[n][h])). a_d term is wave-uniform;
// a_s is a 4B gather (identical address across the 8 lanes of a head).
// No max-subtraction: logits are O(0.5), exp is safe, softmax ratio identical.
__global__ __launch_bounds__(256) void k_agg(
    const float* __restrict__ xp,
    const float* __restrict__ a_s, const float* __restrict__ a_d,
    const int* __restrict__ csr_src, const int* __restrict__ off,
    const float* __restrict__ bias, float* __restrict__ out, int N)
{
    const int wid = threadIdx.x >> 6;
    const int l   = threadIdx.x & 63;
    const int n = blockIdx.x * 4 + wid;
    if (n >= N) return;

    const int nb  = off[n];
    const int deg = off[n + 1] - nb;
    const int hr  = l >> 3;
    const int h   = hr < 6 ? hr : 5;      // clamp for lanes 48..63
    const int lc  = l < 48 ? l : 47;      // clamp for lanes 48..63
    const float4* __restrict__ xp4 = (const float4*)xp;

    const float zd = a_d[(size_t)n * 6 + h];   // wave-uniform per head

    float ax = 0.f, ay = 0.f, az = 0.f, aw = 0.f, se = 0.f;

    if (deg <= 64) {
        // Preload this node's src indices: one per lane, broadcast via shfl.
        int myidx = (l < deg) ? csr_src[nb + l] : 0;
        int i = 0;
        for (; i + 8 <= deg; i += 8) {
            int s[8]; float as[8]; float4 xv[8];
            #pragma unroll
            for (int k = 0; k < 8; ++k) {
                s[k]  = __shfl(myidx, i + k);
                as[k] = a_s[(size_t)s[k] * 6 + h];
            }
            #pragma unroll
            for (int k = 0; k < 8; ++k) xv[k] = xp4[s[k] * 48 + lc];
            #pragma unroll
            for (int k = 0; k < 8; ++k) {
                float z = as[k] + zd;
                z = z > 0.f ? z : 0.2f * z;
                float ev = __expf(z);
                ax = fmaf(ev, xv[k].x, ax);
                ay = fmaf(ev, xv[k].y, ay);
                az = fmaf(ev, xv[k].z, az);
                aw = fmaf(ev, xv[k].w, aw);
                se += ev;
            }
        }
        for (; i < deg; ++i) {
            int sx   = __shfl(myidx, i);
            float z  = a_s[(size_t)sx * 6 + h] + zd;
            z = z > 0.f ? z : 0.2f * z;
            float ev = __expf(z);
            float4 xv = xp4[sx * 48 + lc];
            ax = fmaf(ev, xv.x, ax);
            ay = fmaf(ev, xv.y, ay);
            az = fmaf(ev, xv.z, az);
            aw = fmaf(ev, xv.w, aw);
            se += ev;
        }
    } else {
        // Generic path (deg > 64): direct index loads, 4x unrolled.
        int i = 0;
        for (; i + 4 <= deg; i += 4) {
            int s[4]; float as[4]; float4 xv[4];
            #pragma unroll
            for (int k = 0; k < 4; ++k) {
                s[k]  = csr_src[nb + i + k];
                as[k] = a_s[(size_t)s[k] * 6 + h];
            }
            #pragma unroll
            for (int k = 0; k < 4; ++k) xv[k] = xp4[s[k] * 48 + lc];
            #pragma unroll
            for (int k = 0; k < 4; ++k) {
                float z = as[k] + zd;
                z = z > 0.f ? z : 0.2f * z;
                float ev = __expf(z);
                ax = fmaf(ev, xv[k].x, ax);
                ay = fmaf(ev, xv[k].y, ay);
                az = fmaf(ev, xv[k].z, az);
                aw = fmaf(ev, xv[k].w, aw);
                se += ev;
            }
        }
        for (; i < deg; ++i) {
            int sx   = csr_src[nb + i];
            float z  = a_s[(size_t)sx * 6 + h] + zd;
            z = z > 0.f ? z : 0.2f * z;
            float ev = __expf(z);
            float4 xv = xp4[sx * 48 + lc];
            ax = fmaf(ev, xv.x, ax);
            ay = fmaf(ev, xv.y, ay);
            az = fmaf(ev, xv.z, az);
            aw = fmaf(ev, xv.w, aw);
            se += ev;
        }
    }

    const float inv = 1.f / (se + 1e-16f);
    float v0 = (l < 48) ? ax * inv : 0.f;
    float v1 = (l < 48) ? ay * inv : 0.f;
    float v2 = (l < 48) ? az * inv : 0.f;
    float v3 = (l < 48) ? aw * inv : 0.f;

    // Head mean: sum lanes {l, l+8, ..., l+40} into lanes 0..7.
    #pragma unroll
    for (int d = 8; d <= 32; d <<= 1) {
        v0 += __shfl_down(v0, d);
        v1 += __shfl_down(v1, d);
        v2 += __shfl_down(v2, d);
        v3 += __shfl_down(v3, d);
    }

    if (l < 8) {
        float4 b4 = ((const float4*)bias)[l];
        const float sc = 1.0507009873554805f, al = 1.6732632423543772f;
        float m[4] = {v0 * (1.f / 6.f) + b4.x, v1 * (1.f / 6.f) + b4.y,
                      v2 * (1.f / 6.f) + b4.z, v3 * (1.f / 6.f) + b4.w};
        #pragma unroll
        for (int k = 0; k < 4; ++k)
            m[k] = m[k] > 0.f ? sc * m[k] : sc * al * (__expf(m[k]) - 1.f);
        ((float4*)out)[(size_t)n * 8 + l] = make_float4(m[0], m[1], m[2], m[3]);
    }
}

extern "C" void kernel_launch(void* const* d_in, const int* in_sizes, int n_in,
                              void* d_out, int out_size, void* d_ws, size_t ws_size,
                              hipStream_t stream)
{
    const float* x       = (const float*)d_in[0];
    const int*   ei      = (const int*)d_in[1];   // [2][E] int32
    const float* W       = (const float*)d_in[2];
    const float* att_src = (const float*)d_in[3];
    const float* att_dst = (const float*)d_in[4];
    const float* bias    = (const float*)d_in[5];
    float* out = (float*)d_out;

    const int N = in_sizes[0] / 128;
    const int E = in_sizes[1] / 2;
    const int NB = (N + 1023) / 1024;   // 98 <= 128 (k_bscan capacity)

    char* ws = (char*)d_ws;
    size_t o = 0;
    auto take = [&](size_t bytes) { size_t r = o; o = (o + bytes + 255) & ~(size_t)255; return r; };
    float* xp      = (float*)(ws + take((size_t)N * 192 * 4));
    float* a_s     = (float*)(ws + take((size_t)N * 6 * 4));
    float* a_d     = (float*)(ws + take((size_t)N * 6 * 4));
    int*   off     = (int*)  (ws + take((size_t)(N + 1) * 4));
    int*   degcur  = (int*)  (ws + take((size_t)2 * N * 4));  // deg | cursor
    int*   deg     = degcur;
    int*   cursor  = degcur + N;
    int*   csr_src = (int*)  (ws + take((size_t)E * 4));
    int*   bsum    = (int*)  (ws + take((size_t)NB * 4));
    int*   bbase   = (int*)  (ws + take((size_t)NB * 4));
    (void)ws_size; (void)n_in; (void)out_size;

    hipMemsetAsync(degcur, 0, (size_t)2 * N * 4, stream);

    k_gemm<<<(N + TN - 1) / TN, 256, 0, stream>>>(x, W, att_src, att_dst,
                                                  xp, a_s, a_d, N);
    int eg = (E + 255) / 256;
    k_deg<<<eg, 256, 0, stream>>>(ei, deg, E);
    k_bsum<<<NB, 256, 0, stream>>>(deg, bsum, N);
    k_bscan<<<1, 128, 0, stream>>>(bsum, bbase, NB, off + N);
    k_off<<<NB, 256, 0, stream>>>(deg, bbase, off, N);
    k_scat<<<eg, 256, 0, stream>>>(ei, off, cursor, csr_src, E);
    k_agg<<<(N + 3) / 4, 256, 0, stream>>>(xp, a_s, a_d, csr_src, off, bias, out, N);
}

// Round 4
// 409.470 us; speedup vs baseline: 4.4094x; 1.3417x over previous
//
#include <hip/hip_runtime.h>

// GATConv forward, fp32 in/out, MI355X.
// N=100000 nodes, E=1600000 edges, IN_F=128, HEADS=6, OUT_F=32 (HC=192).
// Pipeline: memset(deg) -> k_gemm (xp[bf16], a_s, a_d) -> k_deg (+rank)
//           -> k_bsum/k_bscan/k_off (hierarchical CSR offset scan)
//           -> k_scat (atomic-free CSR src scatter via rank)
//           -> k_agg (wave-per-node: recompute exp-logits in-register,
//                     bf16 xp gather, softmax aggregation + head-mean + SELU).
//
// R4 changes vs R3:
//   - xp stored as bf16 (RNE): halves the k_agg gather stream (768->384 B/edge)
//     and k_gemm's xp write. Math stays fp32; logits a_s/a_d stay fp32.
//   - k_deg also records rank[e] = atomicAdd(&deg[dst],1); k_scat uses
//     p = off[dst] + rank[e] -> no atomics in the scatter pass, no cursor.

#define TN 64          // nodes per gemm block
#define XS_PAD 68      // [k][n] LDS stride: k*68+8*nt is 16B aligned -> ds_read_b128

__device__ __forceinline__ unsigned short f2bf(float f)
{
    unsigned int u = __float_as_uint(f);
    u = (u + 0x7fffu + ((u >> 16) & 1u)) >> 16;   // round-to-nearest-even
    return (unsigned short)u;
}

__global__ __launch_bounds__(256) void k_gemm(
    const float* __restrict__ x, const float* __restrict__ W,
    const float* __restrict__ att_src, const float* __restrict__ att_dst,
    unsigned short* __restrict__ xpb, float* __restrict__ a_s, float* __restrict__ a_d,
    int N)
{
    __shared__ float xs[128 * XS_PAD];
    const int t  = threadIdx.x;
    const int n0 = blockIdx.x * TN;

    for (int i = t; i < TN * 128; i += 256) {
        int n = i >> 7, k = i & 127;
        int gn = n0 + n;
        float v = 0.f;
        if (gn < N) v = x[gn * 128 + k];
        xs[k * XS_PAD + n] = v;
    }
    __syncthreads();

    const int ct = t & 31;   // column within head (c)
    const int nt = t >> 5;   // node-octet id (0..7)

    float acc[8][6];
    #pragma unroll
    for (int i = 0; i < 8; ++i)
        #pragma unroll
        for (int j = 0; j < 6; ++j) acc[i][j] = 0.f;

    const float* Wp = W + ct;
    for (int k = 0; k < 128; ++k) {
        float w[6];
        #pragma unroll
        for (int j = 0; j < 6; ++j) w[j] = Wp[k * 192 + 32 * j];
        const float4* xr = (const float4*)(xs + k * XS_PAD + nt * 8);
        float4 xa = xr[0];
        float4 xb = xr[1];
        float xv[8] = {xa.x, xa.y, xa.z, xa.w, xb.x, xb.y, xb.z, xb.w};
        #pragma unroll
        for (int i = 0; i < 8; ++i)
            #pragma unroll
            for (int j = 0; j < 6; ++j) acc[i][j] += xv[i] * w[j];
    }

    #pragma unroll
    for (int i = 0; i < 8; ++i) {
        int gn = n0 + nt * 8 + i;
        if (gn < N) {
            #pragma unroll
            for (int j = 0; j < 6; ++j)
                xpb[(size_t)gn * 192 + 32 * j + ct] = f2bf(acc[i][j]);
        }
    }

    float asc[6], adc[6];
    #pragma unroll
    for (int j = 0; j < 6; ++j) {
        asc[j] = att_src[j * 32 + ct];
        adc[j] = att_dst[j * 32 + ct];
    }
    #pragma unroll
    for (int i = 0; i < 8; ++i) {
        int gn = n0 + nt * 8 + i;
        #pragma unroll
        for (int j = 0; j < 6; ++j) {
            float vs = acc[i][j] * asc[j];
            float vd = acc[i][j] * adc[j];
            #pragma unroll
            for (int d = 16; d; d >>= 1) {
                vs += __shfl_down(vs, d, 32);
                vd += __shfl_down(vd, d, 32);
            }
            if (ct == 0 && gn < N) {
                a_s[gn * 6 + j] = vs;
                a_d[gn * 6 + j] = vd;
            }
        }
    }
}

// Degree count + within-segment rank (the atomic's return value).
__global__ void k_deg(const int* __restrict__ ei, int* __restrict__ deg,
                      int* __restrict__ rank, int E)
{
    int e = blockIdx.x * blockDim.x + threadIdx.x;
    if (e < E) rank[e] = atomicAdd(&deg[ei[E + e]], 1);
}

// ---- hierarchical exclusive scan over deg[N] -> off[N+1] ----
__global__ __launch_bounds__(256) void k_bsum(
    const int* __restrict__ deg, int* __restrict__ bsum, int N)
{
    __shared__ int sd[256];
    const int b = blockIdx.x, t = threadIdx.x;
    const int base = b * 1024;
    int s = 0;
    #pragma unroll
    for (int k = 0; k < 4; ++k) {
        int g = base + t + k * 256;
        if (g < N) s += deg[g];
    }
    sd[t] = s;
    __syncthreads();
    for (int o = 128; o; o >>= 1) {
        if (t < o) sd[t] += sd[t + o];
        __syncthreads();
    }
    if (t == 0) bsum[b] = sd[0];
}

__global__ __launch_bounds__(128) void k_bscan(
    const int* __restrict__ bsum, int* __restrict__ bbase,
    int NB, int* __restrict__ offN)
{
    __shared__ int sd[128];
    const int t = threadIdx.x;
    int v = (t < NB) ? bsum[t] : 0;
    sd[t] = v;
    __syncthreads();
    for (int o = 1; o < 128; o <<= 1) {
        int add = (t >= o) ? sd[t - o] : 0;
        __syncthreads();
        sd[t] += add;
        __syncthreads();
    }
    if (t < NB) bbase[t] = sd[t] - v;   // exclusive block base
    if (t == 127) *offN = sd[127];      // grand total -> off[N]
}

__global__ __launch_bounds__(256) void k_off(
    const int* __restrict__ deg, const int* __restrict__ bbase,
    int* __restrict__ off, int N)
{
    __shared__ int sw[256];
    const int b = blockIdx.x, t = threadIdx.x;
    const int base = b * 1024 + t * 4;
    int d[4]; int s = 0;
    #pragma unroll
    for (int k = 0; k < 4; ++k) {
        int g = base + k;
        d[k] = (g < N) ? deg[g] : 0;
        s += d[k];
    }
    sw[t] = s;
    __syncthreads();
    for (int o = 1; o < 256; o <<= 1) {
        int add = (t >= o) ? sw[t - o] : 0;
        __syncthreads();
        sw[t] += add;
        __syncthreads();
    }
    int run = bbase[b] + (sw[t] - s);   // exclusive base for this thread
    #pragma unroll
    for (int k = 0; k < 4; ++k) {
        int g = base + k;
        if (g < N) off[g] = run;
        run += d[k];
    }
}

// Atomic-free CSR scatter: csr_src[off[dst] + rank[e]] = src.
__global__ void k_scat(const int* __restrict__ ei, const int* __restrict__ off,
                       const int* __restrict__ rank, int* __restrict__ csr_src, int E)
{
    int e = blockIdx.x * blockDim.x + threadIdx.x;
    if (e < E) {
        int dst = ei[E + e];
        csr_src[off[dst] + rank[e]] = ei[e];
    }
}

// Wave-per-node aggregation over bf16 xp. Lane l (0..47) owns cols [4l,4l+4)
// of the 192-wide row (head h = l>>3); one uint2 (4 bf16) gather per edge.
// Edge logits recomputed in-register: ev = exp(leakyrelu(a_s[src][h]+a_d[n][h])).
// No max-subtraction: logits are O(0.5), exp safe, softmax ratio identical.
__global__ __launch_bounds__(256) void k_agg(
    const unsigned short* __restrict__ xpb,
    const float* __restrict__ a_s, const float* __restrict__ a_d,
    const int* __restrict__ csr_src, const int* __restrict__ off,
    const float* __restrict__ bias, float* __restrict__ out, int N)
{
    const int wid = threadIdx.x >> 6;
    const int l   = threadIdx.x & 63;
    const int n = blockIdx.x * 4 + wid;
    if (n >= N) return;

    const int nb  = off[n];
    const int deg = off[n + 1] - nb;
    const int hr  = l >> 3;
    const int h   = hr < 6 ? hr : 5;      // clamp for lanes 48..63
    const int lc  = l < 48 ? l : 47;      // clamp for lanes 48..63
    const uint2* __restrict__ xp2 = (const uint2*)xpb;   // 48 uint2 per row

    const float zd = a_d[(size_t)n * 6 + h];   // wave-uniform per head

    float ax = 0.f, ay = 0.f, az = 0.f, aw = 0.f, se = 0.f;

    if (deg <= 64) {
        // Preload this node's src indices: one per lane, broadcast via shfl.
        int myidx = (l < deg) ? csr_src[nb + l] : 0;
        int i = 0;
        for (; i + 8 <= deg; i += 8) {
            int s[8]; float as[8]; uint2 xv[8];
            #pragma unroll
            for (int k = 0; k < 8; ++k) {
                s[k]  = __shfl(myidx, i + k);
                as[k] = a_s[(size_t)s[k] * 6 + h];
            }
            #pragma unroll
            for (int k = 0; k < 8; ++k) xv[k] = xp2[s[k] * 48 + lc];
            #pragma unroll
            for (int k = 0; k < 8; ++k) {
                float z = as[k] + zd;
                z = z > 0.f ? z : 0.2f * z;
                float ev = __expf(z);
                float f0 = __uint_as_float(xv[k].x << 16);
                float f1 = __uint_as_float(xv[k].x & 0xffff0000u);
                float f2 = __uint_as_float(xv[k].y << 16);
                float f3 = __uint_as_float(xv[k].y & 0xffff0000u);
                ax = fmaf(ev, f0, ax);
                ay = fmaf(ev, f1, ay);
                az = fmaf(ev, f2, az);
                aw = fmaf(ev, f3, aw);
                se += ev;
            }
        }
        for (; i < deg; ++i) {
            int sx   = __shfl(myidx, i);
            float z  = a_s[(size_t)sx * 6 + h] + zd;
            z = z > 0.f ? z : 0.2f * z;
            float ev = __expf(z);
            uint2 xv = xp2[sx * 48 + lc];
            float f0 = __uint_as_float(xv.x << 16);
            float f1 = __uint_as_float(xv.x & 0xffff0000u);
            float f2 = __uint_as_float(xv.y << 16);
            float f3 = __uint_as_float(xv.y & 0xffff0000u);
            ax = fmaf(ev, f0, ax);
            ay = fmaf(ev, f1, ay);
            az = fmaf(ev, f2, az);
            aw = fmaf(ev, f3, aw);
            se += ev;
        }
    } else {
        // Generic path (deg > 64): direct index loads, 4x unrolled.
        int i = 0;
        for (; i + 4 <= deg; i += 4) {
            int s[4]; float as[4]; uint2 xv[4];
            #pragma unroll
            for (int k = 0; k < 4; ++k) {
                s[k]  = csr_src[nb + i + k];
                as[k] = a_s[(size_t)s[k] * 6 + h];
            }
            #pragma unroll
            for (int k = 0; k < 4; ++k) xv[k] = xp2[s[k] * 48 + lc];
            #pragma unroll
            for (int k = 0; k < 4; ++k) {
                float z = as[k] + zd;
                z = z > 0.f ? z : 0.2f * z;
                float ev = __expf(z);
                float f0 = __uint_as_float(xv[k].x << 16);
                float f1 = __uint_as_float(xv[k].x & 0xffff0000u);
                float f2 = __uint_as_float(xv[k].y << 16);
                float f3 = __uint_as_float(xv[k].y & 0xffff0000u);
                ax = fmaf(ev, f0, ax);
                ay = fmaf(ev, f1, ay);
                az = fmaf(ev, f2, az);
                aw = fmaf(ev, f3, aw);
                se += ev;
            }
        }
        for (; i < deg; ++i) {
            int sx   = csr_src[nb + i];
            float z  = a_s[(size_t)sx * 6 + h] + zd;
            z = z > 0.f ? z : 0.2f * z;
            float ev = __expf(z);
            uint2 xv = xp2[sx * 48 + lc];
            float f0 = __uint_as_float(xv.x << 16);
            float f1 = __uint_as_float(xv.x & 0xffff0000u);
            float f2 = __uint_as_float(xv.y << 16);
            float f3 = __uint_as_float(xv.y & 0xffff0000u);
            ax = fmaf(ev, f0, ax);
            ay = fmaf(ev, f1, ay);
            az = fmaf(ev, f2, az);
            aw = fmaf(ev, f3, aw);
            se += ev;
        }
    }

    const float inv = 1.f / (se + 1e-16f);
    float v0 = (l < 48) ? ax * inv : 0.f;
    float v1 = (l < 48) ? ay * inv : 0.f;
    float v2 = (l < 48) ? az * inv : 0.f;
    float v3 = (l < 48) ? aw * inv : 0.f;

    // Head mean: sum lanes {l, l+8, ..., l+40} into lanes 0..7.
    #pragma unroll
    for (int d = 8; d <= 32; d <<= 1) {
        v0 += __shfl_down(v0, d);
        v1 += __shfl_down(v1, d);
        v2 += __shfl_down(v2, d);
        v3 += __shfl_down(v3, d);
    }

    if (l < 8) {
        float4 b4 = ((const float4*)bias)[l];
        const float sc = 1.0507009873554805f, al = 1.6732632423543772f;
        float m[4] = {v0 * (1.f / 6.f) + b4.x, v1 * (1.f / 6.f) + b4.y,
                      v2 * (1.f / 6.f) + b4.z, v3 * (1.f / 6.f) + b4.w};
        #pragma unroll
        for (int k = 0; k < 4; ++k)
            m[k] = m[k] > 0.f ? sc * m[k] : sc * al * (__expf(m[k]) - 1.f);
        ((float4*)out)[(size_t)n * 8 + l] = make_float4(m[0], m[1], m[2], m[3]);
    }
}

extern "C" void kernel_launch(void* const* d_in, const int* in_sizes, int n_in,
                              void* d_out, int out_size, void* d_ws, size_t ws_size,
                              hipStream_t stream)
{
    const float* x       = (const float*)d_in[0];
    const int*   ei      = (const int*)d_in[1];   // [2][E] int32
    const float* W       = (const float*)d_in[2];
    const float* att_src = (const float*)d_in[3];
    const float* att_dst = (const float*)d_in[4];
    const float* bias    = (const float*)d_in[5];
    float* out = (float*)d_out;

    const int N = in_sizes[0] / 128;
    const int E = in_sizes[1] / 2;
    const int NB = (N + 1023) / 1024;   // 98 <= 128 (k_bscan capacity)

    char* ws = (char*)d_ws;
    size_t o = 0;
    auto take = [&](size_t bytes) { size_t r = o; o = (o + bytes + 255) & ~(size_t)255; return r; };
    unsigned short* xpb = (unsigned short*)(ws + take((size_t)N * 192 * 2));
    float* a_s     = (float*)(ws + take((size_t)N * 6 * 4));
    float* a_d     = (float*)(ws + take((size_t)N * 6 * 4));
    int*   off     = (int*)  (ws + take((size_t)(N + 1) * 4));
    int*   deg     = (int*)  (ws + take((size_t)N * 4));
    int*   rank    = (int*)  (ws + take((size_t)E * 4));
    int*   csr_src = (int*)  (ws + take((size_t)E * 4));
    int*   bsum    = (int*)  (ws + take((size_t)NB * 4));
    int*   bbase   = (int*)  (ws + take((size_t)NB * 4));
    (void)ws_size; (void)n_in; (void)out_size;

    hipMemsetAsync(deg, 0, (size_t)N * 4, stream);

    k_gemm<<<(N + TN - 1) / TN, 256, 0, stream>>>(x, W, att_src, att_dst,
                                                  xpb, a_s, a_d, N);
    int eg = (E + 255) / 256;
    k_deg<<<eg, 256, 0, stream>>>(ei, deg, rank, E);
    k_bsum<<<NB, 256, 0, stream>>>(deg, bsum, N);
    k_bscan<<<1, 128, 0, stream>>>(bsum, bbase, NB, off + N);
    k_off<<<NB, 256, 0, stream>>>(deg, bbase, off, N);
    k_scat<<<eg, 256, 0, stream>>>(ei, off, rank, csr_src, E);
    k_agg<<<(N + 3) / 4, 256, 0, stream>>>(xpb, a_s, a_d, csr_src, off, bias, out, N);
}

// Round 5
// 340.330 us; speedup vs baseline: 5.3052x; 1.2032x over previous
//
#include <hip/hip_runtime.h>

// GATConv forward, fp32 in/out, MI355X.
// N=100000 nodes, E=1600000 edges, IN_F=128, HEADS=6, OUT_F=32 (HC=192).
// Pipeline: memset(deg) -> k_gemm (MFMA bf16: xp[bf16]) -> k_att (a_s,a_d)
//           -> k_deg (+rank) -> k_bsum/k_bscan/k_off (CSR offset scan)
//           -> k_scat (atomic-free CSR src scatter)
//           -> k_agg (wave-per-node softmax aggregation + head-mean + SELU).
//
// R5 changes vs R4:
//   - k_gemm rewritten with v_mfma_f32_16x16x32_bf16 (was fp32 VALU, 123us,
//     MfmaUtil=0). Block=4 waves=64 rows; x staged to LDS bf16 [m][k] stride
//     136 (2-way bank conflicts only = free); each wave owns 48 cols, its 12
//     W-frags (fp32->bf16) live in registers across the block.
//     A-operand layout: A[m=lane&15][k=quad*8+j]; B: B[k=quad*8+j][n=lane&15];
//     C/D: row=quad*4+reg, col=lane&15 (learn_hip m89/m91-verified).
//   - a_s/a_d now computed by k_att (one thread per (n,h), reads xpb).

typedef __attribute__((ext_vector_type(8))) short short8;
typedef __attribute__((ext_vector_type(4))) float f32x4;

#define SK 136   // LDS k-stride (bf16 elems) for the x tile: 272 B/row

__device__ __forceinline__ unsigned short f2bf(float f)
{
    unsigned int u = __float_as_uint(f);
    u = (u + 0x7fffu + ((u >> 16) & 1u)) >> 16;   // round-to-nearest-even
    return (unsigned short)u;
}
__device__ __forceinline__ float bf2f(unsigned int lo16)
{
    return __uint_as_float(lo16 << 16);
}

// MFMA projection: xpb[n][192] (bf16) = x[n][128] @ W[128][192], bf16 inputs,
// fp32 accumulate.
__global__ __launch_bounds__(256) void k_gemm(
    const float* __restrict__ x, const float* __restrict__ W,
    unsigned short* __restrict__ xpb, int N)
{
    __shared__ unsigned short xt[64 * SK];
    const int t    = threadIdx.x;
    const int wave = t >> 6;
    const int lane = t & 63;
    const int ln   = lane & 15;          // n (B) / m (A) index within tile
    const int q    = lane >> 4;          // quad: k-octet selector
    const int n0   = blockIdx.x * 64;
    const int cb   = wave * 48;          // this wave's first output col

    // Stage x tile (64 rows x 128 cols fp32) -> LDS bf16 [m][k], stride SK.
    {
        const float4* x4 = (const float4*)x;
        #pragma unroll
        for (int it = 0; it < 8; ++it) {
            int i   = t + it * 256;      // 0..2047
            int row = i >> 5;
            int c4  = i & 31;            // float4 index within row
            int gr  = n0 + row;
            if (gr > N - 1) gr = N - 1;  // clamp; stores are guarded later
            float4 f = x4[(size_t)gr * 32 + c4];
            unsigned int u0 = (unsigned int)f2bf(f.x) | ((unsigned int)f2bf(f.y) << 16);
            unsigned int u1 = (unsigned int)f2bf(f.z) | ((unsigned int)f2bf(f.w) << 16);
            *(uint2*)(xt + row * SK + c4 * 4) = make_uint2(u0, u1);
        }
    }

    // B fragments: 3 n-tiles x 4 k-blocks, 8 bf16/lane each, in registers.
    short8 bw[3][4];
    #pragma unroll
    for (int nt = 0; nt < 3; ++nt)
        #pragma unroll
        for (int kbi = 0; kbi < 4; ++kbi) {
            short8 v;
            #pragma unroll
            for (int j = 0; j < 8; ++j) {
                int k = kbi * 32 + q * 8 + j;
                v[j] = (short)f2bf(W[k * 192 + cb + nt * 16 + ln]);
            }
            bw[nt][kbi] = v;
        }

    __syncthreads();

    f32x4 acc[4][3];
    #pragma unroll
    for (int mt = 0; mt < 4; ++mt)
        #pragma unroll
        for (int nt = 0; nt < 3; ++nt) acc[mt][nt] = (f32x4)0.f;

    #pragma unroll
    for (int kbi = 0; kbi < 4; ++kbi) {
        #pragma unroll
        for (int mt = 0; mt < 4; ++mt) {
            short8 av = *(const short8*)(xt + (mt * 16 + ln) * SK + kbi * 32 + q * 8);
            #pragma unroll
            for (int nt = 0; nt < 3; ++nt)
                acc[mt][nt] = __builtin_amdgcn_mfma_f32_16x16x32_bf16(
                    av, bw[nt][kbi], acc[mt][nt], 0, 0, 0);
        }
    }

    // Epilogue: C row = quad*4 + reg, col = lane&15 (within each 16x16 tile).
    #pragma unroll
    for (int mt = 0; mt < 4; ++mt) {
        #pragma unroll
        for (int r = 0; r < 4; ++r) {
            int grow = n0 + mt * 16 + q * 4 + r;
            if (grow < N) {
                #pragma unroll
                for (int nt = 0; nt < 3; ++nt)
                    xpb[(size_t)grow * 192 + cb + nt * 16 + ln] = f2bf(acc[mt][nt][r]);
            }
        }
    }
}

// Per-node attention logit halves from xpb: one thread per (n,h).
__global__ __launch_bounds__(256) void k_att(
    const unsigned short* __restrict__ xpb,
    const float* __restrict__ att_src, const float* __restrict__ att_dst,
    float* __restrict__ a_s, float* __restrict__ a_d, int N)
{
    int idx = blockIdx.x * 256 + threadIdx.x;
    if (idx >= N * 6) return;
    int n = idx / 6, h = idx - n * 6;
    const uint2* p = (const uint2*)(xpb + (size_t)n * 192 + h * 32);
    float s = 0.f, d = 0.f;
    #pragma unroll
    for (int u = 0; u < 8; ++u) {            // 8 x uint2 = 32 bf16
        uint2 v = p[u];
        unsigned int w[4] = {v.x & 0xffffu, v.x >> 16, v.y & 0xffffu, v.y >> 16};
        #pragma unroll
        for (int j = 0; j < 4; ++j) {
            float xv = bf2f(w[j]);
            int c = u * 4 + j;
            s = fmaf(xv, att_src[h * 32 + c], s);
            d = fmaf(xv, att_dst[h * 32 + c], d);
        }
    }
    a_s[idx] = s;
    a_d[idx] = d;
}

// Degree count + within-segment rank (the atomic's return value).
__global__ void k_deg(const int* __restrict__ ei, int* __restrict__ deg,
                      int* __restrict__ rank, int E)
{
    int e = blockIdx.x * blockDim.x + threadIdx.x;
    if (e < E) rank[e] = atomicAdd(&deg[ei[E + e]], 1);
}

// ---- hierarchical exclusive scan over deg[N] -> off[N+1] ----
__global__ __launch_bounds__(256) void k_bsum(
    const int* __restrict__ deg, int* __restrict__ bsum, int N)
{
    __shared__ int sd[256];
    const int b = blockIdx.x, t = threadIdx.x;
    const int base = b * 1024;
    int s = 0;
    #pragma unroll
    for (int k = 0; k < 4; ++k) {
        int g = base + t + k * 256;
        if (g < N) s += deg[g];
    }
    sd[t] = s;
    __syncthreads();
    for (int o = 128; o; o >>= 1) {
        if (t < o) sd[t] += sd[t + o];
        __syncthreads();
    }
    if (t == 0) bsum[b] = sd[0];
}

__global__ __launch_bounds__(128) void k_bscan(
    const int* __restrict__ bsum, int* __restrict__ bbase,
    int NB, int* __restrict__ offN)
{
    __shared__ int sd[128];
    const int t = threadIdx.x;
    int v = (t < NB) ? bsum[t] : 0;
    sd[t] = v;
    __syncthreads();
    for (int o = 1; o < 128; o <<= 1) {
        int add = (t >= o) ? sd[t - o] : 0;
        __syncthreads();
        sd[t] += add;
        __syncthreads();
    }
    if (t < NB) bbase[t] = sd[t] - v;   // exclusive block base
    if (t == 127) *offN = sd[127];      // grand total -> off[N]
}

__global__ __launch_bounds__(256) void k_off(
    const int* __restrict__ deg, const int* __restrict__ bbase,
    int* __restrict__ off, int N)
{
    __shared__ int sw[256];
    const int b = blockIdx.x, t = threadIdx.x;
    const int base = b * 1024 + t * 4;
    int d[4]; int s = 0;
    #pragma unroll
    for (int k = 0; k < 4; ++k) {
        int g = base + k;
        d[k] = (g < N) ? deg[g] : 0;
        s += d[k];
    }
    sw[t] = s;
    __syncthreads();
    for (int o = 1; o < 256; o <<= 1) {
        int add = (t >= o) ? sw[t - o] : 0;
        __syncthreads();
        sw[t] += add;
        __syncthreads();
    }
    int run = bbase[b] + (sw[t] - s);
    #pragma unroll
    for (int k = 0; k < 4; ++k) {
        int g = base + k;
        if (g < N) off[g] = run;
        run += d[k];
    }
}

// Atomic-free CSR scatter: csr_src[off[dst] + rank[e]] = src.
__global__ void k_scat(const int* __restrict__ ei, const int* __restrict__ off,
                       const int* __restrict__ rank, int* __restrict__ csr_src, int E)
{
    int e = blockIdx.x * blockDim.x + threadIdx.x;
    if (e < E) {
        int dst = ei[E + e];
        csr_src[off[dst] + rank[e]] = ei[e];
    }
}

// Wave-per-node aggregation over bf16 xp. Lane l (0..47) owns cols [4l,4l+4)
// of the 192-wide row (head h = l>>3); one uint2 (4 bf16) gather per edge.
// Edge logits recomputed in-register: ev = exp(leakyrelu(a_s[src][h]+a_d[n][h])).
__global__ __launch_bounds__(256) void k_agg(
    const unsigned short* __restrict__ xpb,
    const float* __restrict__ a_s, const float* __restrict__ a_d,
    const int* __restrict__ csr_src, const int* __restrict__ off,
    const float* __restrict__ bias, float* __restrict__ out, int N)
{
    const int wid = threadIdx.x >> 6;
    const int l   = threadIdx.x & 63;
    const int n = blockIdx.x * 4 + wid;
    if (n >= N) return;

    const int nb  = off[n];
    const int deg = off[n + 1] - nb;
    const int hr  = l >> 3;
    const int h   = hr < 6 ? hr : 5;      // clamp for lanes 48..63
    const int lc  = l < 48 ? l : 47;      // clamp for lanes 48..63
    const uint2* __restrict__ xp2 = (const uint2*)xpb;   // 48 uint2 per row

    const float zd = a_d[(size_t)n * 6 + h];   // wave-uniform per head

    float ax = 0.f, ay = 0.f, az = 0.f, aw = 0.f, se = 0.f;

    if (deg <= 64) {
        int myidx = (l < deg) ? csr_src[nb + l] : 0;
        int i = 0;
        for (; i + 8 <= deg; i += 8) {
            int s[8]; float as[8]; uint2 xv[8];
            #pragma unroll
            for (int k = 0; k < 8; ++k) {
                s[k]  = __shfl(myidx, i + k);
                as[k] = a_s[(size_t)s[k] * 6 + h];
            }
            #pragma unroll
            for (int k = 0; k < 8; ++k) xv[k] = xp2[s[k] * 48 + lc];
            #pragma unroll
            for (int k = 0; k < 8; ++k) {
                float z = as[k] + zd;
                z = z > 0.f ? z : 0.2f * z;
                float ev = __expf(z);
                ax = fmaf(ev, __uint_as_float(xv[k].x << 16), ax);
                ay = fmaf(ev, __uint_as_float(xv[k].x & 0xffff0000u), ay);
                az = fmaf(ev, __uint_as_float(xv[k].y << 16), az);
                aw = fmaf(ev, __uint_as_float(xv[k].y & 0xffff0000u), aw);
                se += ev;
            }
        }
        for (; i < deg; ++i) {
            int sx   = __shfl(myidx, i);
            float z  = a_s[(size_t)sx * 6 + h] + zd;
            z = z > 0.f ? z : 0.2f * z;
            float ev = __expf(z);
            uint2 xv = xp2[sx * 48 + lc];
            ax = fmaf(ev, __uint_as_float(xv.x << 16), ax);
            ay = fmaf(ev, __uint_as_float(xv.x & 0xffff0000u), ay);
            az = fmaf(ev, __uint_as_float(xv.y << 16), az);
            aw = fmaf(ev, __uint_as_float(xv.y & 0xffff0000u), aw);
            se += ev;
        }
    } else {
        int i = 0;
        for (; i + 4 <= deg; i += 4) {
            int s[4]; float as[4]; uint2 xv[4];
            #pragma unroll
            for (int k = 0; k < 4; ++k) {
                s[k]  = csr_src[nb + i + k];
                as[k] = a_s[(size_t)s[k] * 6 + h];
            }
            #pragma unroll
            for (int k = 0; k < 4; ++k) xv[k] = xp2[s[k] * 48 + lc];
            #pragma unroll
            for (int k = 0; k < 4; ++k) {
                float z = as[k] + zd;
                z = z > 0.f ? z : 0.2f * z;
                float ev = __expf(z);
                ax = fmaf(ev, __uint_as_float(xv[k].x << 16), ax);
                ay = fmaf(ev, __uint_as_float(xv[k].x & 0xffff0000u), ay);
                az = fmaf(ev, __uint_as_float(xv[k].y << 16), az);
                aw = fmaf(ev, __uint_as_float(xv[k].y & 0xffff0000u), aw);
                se += ev;
            }
        }
        for (; i < deg; ++i) {
            int sx   = csr_src[nb + i];
            float z  = a_s[(size_t)sx * 6 + h] + zd;
            z = z > 0.f ? z : 0.2f * z;
            float ev = __expf(z);
            uint2 xv = xp2[sx * 48 + lc];
            ax = fmaf(ev, __uint_as_float(xv.x << 16), ax);
            ay = fmaf(ev, __uint_as_float(xv.x & 0xffff0000u), ay);
            az = fmaf(ev, __uint_as_float(xv.y << 16), az);
            aw = fmaf(ev, __uint_as_float(xv.y & 0xffff0000u), aw);
            se += ev;
        }
    }

    const float inv = 1.f / (se + 1e-16f);
    float v0 = (l < 48) ? ax * inv : 0.f;
    float v1 = (l < 48) ? ay * inv : 0.f;
    float v2 = (l < 48) ? az * inv : 0.f;
    float v3 = (l < 48) ? aw * inv : 0.f;

    #pragma unroll
    for (int d = 8; d <= 32; d <<= 1) {
        v0 += __shfl_down(v0, d);
        v1 += __shfl_down(v1, d);
        v2 += __shfl_down(v2, d);
        v3 += __shfl_down(v3, d);
    }

    if (l < 8) {
        float4 b4 = ((const float4*)bias)[l];
        const float sc = 1.0507009873554805f, al = 1.6732632423543772f;
        float m[4] = {v0 * (1.f / 6.f) + b4.x, v1 * (1.f / 6.f) + b4.y,
                      v2 * (1.f / 6.f) + b4.z, v3 * (1.f / 6.f) + b4.w};
        #pragma unroll
        for (int k = 0; k < 4; ++k)
            m[k] = m[k] > 0.f ? sc * m[k] : sc * al * (__expf(m[k]) - 1.f);
        ((float4*)out)[(size_t)n * 8 + l] = make_float4(m[0], m[1], m[2], m[3]);
    }
}

extern "C" void kernel_launch(void* const* d_in, const int* in_sizes, int n_in,
                              void* d_out, int out_size, void* d_ws, size_t ws_size,
                              hipStream_t stream)
{
    const float* x       = (const float*)d_in[0];
    const int*   ei      = (const int*)d_in[1];   // [2][E] int32
    const float* W       = (const float*)d_in[2];
    const float* att_src = (const float*)d_in[3];
    const float* att_dst = (const float*)d_in[4];
    const float* bias    = (const float*)d_in[5];
    float* out = (float*)d_out;

    const int N = in_sizes[0] / 128;
    const int E = in_sizes[1] / 2;
    const int NB = (N + 1023) / 1024;   // 98 <= 128 (k_bscan capacity)

    char* ws = (char*)d_ws;
    size_t o = 0;
    auto take = [&](size_t bytes) { size_t r = o; o = (o + bytes + 255) & ~(size_t)255; return r; };
    unsigned short* xpb = (unsigned short*)(ws + take((size_t)N * 192 * 2));
    float* a_s     = (float*)(ws + take((size_t)N * 6 * 4));
    float* a_d     = (float*)(ws + take((size_t)N * 6 * 4));
    int*   off     = (int*)  (ws + take((size_t)(N + 1) * 4));
    int*   deg     = (int*)  (ws + take((size_t)N * 4));
    int*   rank    = (int*)  (ws + take((size_t)E * 4));
    int*   csr_src = (int*)  (ws + take((size_t)E * 4));
    int*   bsum    = (int*)  (ws + take((size_t)NB * 4));
    int*   bbase   = (int*)  (ws + take((size_t)NB * 4));
    (void)ws_size; (void)n_in; (void)out_size;

    hipMemsetAsync(deg, 0, (size_t)N * 4, stream);

    k_gemm<<<(N + 63) / 64, 256, 0, stream>>>(x, W, xpb, N);
    k_att<<<(N * 6 + 255) / 256, 256, 0, stream>>>(xpb, att_src, att_dst, a_s, a_d, N);
    int eg = (E + 255) / 256;
    k_deg<<<eg, 256, 0, stream>>>(ei, deg, rank, E);
    k_bsum<<<NB, 256, 0, stream>>>(deg, bsum, N);
    k_bscan<<<1, 128, 0, stream>>>(bsum, bbase, NB, off + N);
    k_off<<<NB, 256, 0, stream>>>(deg, bbase, off, N);
    k_scat<<<eg, 256, 0, stream>>>(ei, off, rank, csr_src, E);
    k_agg<<<(N + 3) / 4, 256, 0, stream>>>(xpb, a_s, a_d, csr_src, off, bias, out, N);
}

// Round 6
// 316.849 us; speedup vs baseline: 5.6984x; 1.0741x over previous
//
#include <hip/hip_runtime.h>

// GATConv forward, fp32 in/out, MI355X.
// N=100000 nodes, E=1600000 edges, IN_F=128, HEADS=6, OUT_F=32 (HC=192).
// Pipeline: memset(deg) -> k_gemm (MFMA bf16 xp + fused a_s/a_d)
//           -> k_deg (+rank) -> k_bsum -> k_off (scan, bscan folded in)
//           -> k_scat (atomic-free CSR src scatter)
//           -> k_agg (wave-per-node softmax aggregation + head-mean + SELU).
//
// R6 changes vs R5:
//   - k_att fused into k_gemm: MFMA accs spilled to LDS (bf16, stride 200),
//     per-(row,head) dot with att vectors (staged in LDS) -> a_s/a_d. One
//     dispatch + one 38MB xpb re-read eliminated.
//   - k_bscan folded into k_off: each block reduces bsum[0..b) itself.
//   - k_agg: broadcast s*3; addressing via s3*128+lc8 / s3*8+h4 (mad_u24-able)
//     instead of mul48/mul6 chains.

typedef __attribute__((ext_vector_type(8))) short short8;
typedef __attribute__((ext_vector_type(4))) float f32x4;

#define SK 136   // LDS k-stride (bf16 elems) for the x tile: 272 B/row
#define SP 200   // LDS stride (bf16 elems) for the xp spill: 400 B/row

__device__ __forceinline__ unsigned short f2bf(float f)
{
    unsigned int u = __float_as_uint(f);
    u = (u + 0x7fffu + ((u >> 16) & 1u)) >> 16;   // round-to-nearest-even
    return (unsigned short)u;
}
__device__ __forceinline__ float bf2f(unsigned int lo16)
{
    return __uint_as_float(lo16 << 16);
}

// MFMA projection + fused attention halves.
// xpb[n][192] (bf16) = x[n][128] @ W[128][192]; a_s/a_d[n][h] = <xp[n,h,:],att>.
__global__ __launch_bounds__(256) void k_gemm(
    const float* __restrict__ x, const float* __restrict__ W,
    const float* __restrict__ att_src, const float* __restrict__ att_dst,
    unsigned short* __restrict__ xpb, float* __restrict__ a_s, float* __restrict__ a_d,
    int N)
{
    __shared__ __align__(16) unsigned short smem[64 * SP];  // xt(64xSK) then xp(64xSP)
    __shared__ float s_att[2][192];
    const int t    = threadIdx.x;
    const int wave = t >> 6;
    const int lane = t & 63;
    const int ln   = lane & 15;          // n (B) / m (A) index within tile
    const int q    = lane >> 4;          // quad: k-octet selector
    const int n0   = blockIdx.x * 64;
    const int cb   = wave * 48;          // this wave's first output col

    if (t < 192) {
        s_att[0][t] = att_src[t];
        s_att[1][t] = att_dst[t];
    }

    // Stage x tile (64 rows x 128 cols fp32) -> LDS bf16 [m][k], stride SK.
    {
        const float4* x4 = (const float4*)x;
        #pragma unroll
        for (int it = 0; it < 8; ++it) {
            int i   = t + it * 256;      // 0..2047
            int row = i >> 5;
            int c4  = i & 31;            // float4 index within row
            int gr  = n0 + row;
            if (gr > N - 1) gr = N - 1;  // clamp; stores are guarded later
            float4 f = x4[(size_t)gr * 32 + c4];
            unsigned int u0 = (unsigned int)f2bf(f.x) | ((unsigned int)f2bf(f.y) << 16);
            unsigned int u1 = (unsigned int)f2bf(f.z) | ((unsigned int)f2bf(f.w) << 16);
            *(uint2*)(smem + row * SK + c4 * 4) = make_uint2(u0, u1);
        }
    }

    // B fragments: 3 n-tiles x 4 k-blocks, 8 bf16/lane each, in registers.
    short8 bw[3][4];
    #pragma unroll
    for (int nt = 0; nt < 3; ++nt)
        #pragma unroll
        for (int kbi = 0; kbi < 4; ++kbi) {
            short8 v;
            #pragma unroll
            for (int j = 0; j < 8; ++j) {
                int k = kbi * 32 + q * 8 + j;
                v[j] = (short)f2bf(W[k * 192 + cb + nt * 16 + ln]);
            }
            bw[nt][kbi] = v;
        }

    __syncthreads();

    f32x4 acc[4][3];
    #pragma unroll
    for (int mt = 0; mt < 4; ++mt)
        #pragma unroll
        for (int nt = 0; nt < 3; ++nt) acc[mt][nt] = (f32x4)0.f;

    #pragma unroll
    for (int kbi = 0; kbi < 4; ++kbi) {
        #pragma unroll
        for (int mt = 0; mt < 4; ++mt) {
            short8 av = *(const short8*)(smem + (mt * 16 + ln) * SK + kbi * 32 + q * 8);
            #pragma unroll
            for (int nt = 0; nt < 3; ++nt)
                acc[mt][nt] = __builtin_amdgcn_mfma_f32_16x16x32_bf16(
                    av, bw[nt][kbi], acc[mt][nt], 0, 0, 0);
        }
    }

    __syncthreads();   // all xt reads done; smem is reused as the xp spill

    // Epilogue: C row = quad*4 + reg, col = lane&15 (within each 16x16 tile).
    // Write bf16 to both global xpb and the LDS spill.
    #pragma unroll
    for (int mt = 0; mt < 4; ++mt) {
        #pragma unroll
        for (int r = 0; r < 4; ++r) {
            int row  = mt * 16 + q * 4 + r;
            int grow = n0 + row;
            #pragma unroll
            for (int nt = 0; nt < 3; ++nt) {
                unsigned short b = f2bf(acc[mt][nt][r]);
                smem[row * SP + cb + nt * 16 + ln] = b;
                if (grow < N)
                    xpb[(size_t)grow * 192 + cb + nt * 16 + ln] = b;
            }
        }
    }

    __syncthreads();

    // Fused attention halves: 384 (row,head) tasks over 256 threads.
    #pragma unroll
    for (int id = t; id < 384; id += 256) {
        int row = id / 6, h = id - row * 6;
        int gn = n0 + row;
        if (gn < N) {
            const unsigned int* p32 = (const unsigned int*)(smem + row * SP + h * 32);
            float s = 0.f, d = 0.f;
            #pragma unroll
            for (int u = 0; u < 16; ++u) {
                unsigned int v = p32[u];
                float x0 = bf2f(v & 0xffffu);
                float x1 = bf2f(v >> 16);
                s = fmaf(x0, s_att[0][h * 32 + u * 2], s);
                s = fmaf(x1, s_att[0][h * 32 + u * 2 + 1], s);
                d = fmaf(x0, s_att[1][h * 32 + u * 2], d);
                d = fmaf(x1, s_att[1][h * 32 + u * 2 + 1], d);
            }
            a_s[(size_t)gn * 6 + h] = s;
            a_d[(size_t)gn * 6 + h] = d;
        }
    }
}

// Degree count + within-segment rank (the atomic's return value).
__global__ void k_deg(const int* __restrict__ ei, int* __restrict__ deg,
                      int* __restrict__ rank, int E)
{
    int e = blockIdx.x * blockDim.x + threadIdx.x;
    if (e < E) rank[e] = atomicAdd(&deg[ei[E + e]], 1);
}

// Per-1024-chunk sums of deg.
__global__ __launch_bounds__(256) void k_bsum(
    const int* __restrict__ deg, int* __restrict__ bsum, int N)
{
    __shared__ int sd[256];
    const int b = blockIdx.x, t = threadIdx.x;
    const int base = b * 1024;
    int s = 0;
    #pragma unroll
    for (int k = 0; k < 4; ++k) {
        int g = base + t + k * 256;
        if (g < N) s += deg[g];
    }
    sd[t] = s;
    __syncthreads();
    for (int o = 128; o; o >>= 1) {
        if (t < o) sd[t] += sd[t + o];
        __syncthreads();
    }
    if (t == 0) bsum[b] = sd[0];
}

// Offsets: block b reduces bsum[0..b) itself (NB<=128), then local scan.
// Last block also writes off[N] = grand total.
__global__ __launch_bounds__(256) void k_off(
    const int* __restrict__ deg, const int* __restrict__ bsum,
    int* __restrict__ off, int N, int NB)
{
    __shared__ int sw[256];
    __shared__ int sbase;
    const int b = blockIdx.x, t = threadIdx.x;

    sw[t] = (t < b) ? bsum[t] : 0;
    __syncthreads();
    for (int o = 128; o; o >>= 1) {
        if (t < o) sw[t] += sw[t + o];
        __syncthreads();
    }
    if (t == 0) sbase = sw[0];
    __syncthreads();

    const int base = b * 1024 + t * 4;
    int d[4]; int s = 0;
    #pragma unroll
    for (int k = 0; k < 4; ++k) {
        int g = base + k;
        d[k] = (g < N) ? deg[g] : 0;
        s += d[k];
    }
    sw[t] = s;
    __syncthreads();
    for (int o = 1; o < 256; o <<= 1) {
        int add = (t >= o) ? sw[t - o] : 0;
        __syncthreads();
        sw[t] += add;
        __syncthreads();
    }
    int run = sbase + (sw[t] - s);
    #pragma unroll
    for (int k = 0; k < 4; ++k) {
        int g = base + k;
        if (g < N) off[g] = run;
        run += d[k];
    }
    if (b == NB - 1 && t == 255) off[N] = sbase + sw[255];
}

// Atomic-free CSR scatter: csr_src[off[dst] + rank[e]] = src.
__global__ void k_scat(const int* __restrict__ ei, const int* __restrict__ off,
                       const int* __restrict__ rank, int* __restrict__ csr_src, int E)
{
    int e = blockIdx.x * blockDim.x + threadIdx.x;
    if (e < E) {
        int dst = ei[E + e];
        csr_src[off[dst] + rank[e]] = ei[e];
    }
}

// Wave-per-node aggregation over bf16 xp. Lane l (0..47) owns cols [4l,4l+4)
// of the 192-wide row (head h = l>>3); one uint2 (4 bf16) gather per edge.
// Edge logits recomputed in-register: ev = exp(leakyrelu(a_s[src][h]+a_d[n][h])).
// Addressing: broadcast s3 = src*3; xp byte off = s3*128 + lc*8, a_s byte off
// = s3*8 + h*4 (both single v_mad_u32_u24-able).
__global__ __launch_bounds__(256) void k_agg(
    const unsigned short* __restrict__ xpb,
    const float* __restrict__ a_s, const float* __restrict__ a_d,
    const int* __restrict__ csr_src, const int* __restrict__ off,
    const float* __restrict__ bias, float* __restrict__ out, int N)
{
    const int wid = threadIdx.x >> 6;
    const int l   = threadIdx.x & 63;
    const int n = blockIdx.x * 4 + wid;
    if (n >= N) return;

    const int nb  = off[n];
    const int deg = off[n + 1] - nb;
    const int hr  = l >> 3;
    const int h   = hr < 6 ? hr : 5;      // clamp for lanes 48..63
    const int lc  = l < 48 ? l : 47;      // clamp for lanes 48..63
    const unsigned lcb = (unsigned)lc * 8u;
    const unsigned h4  = (unsigned)h * 4u;
    const char* __restrict__ xpB = (const char*)xpb;
    const char* __restrict__ asB = (const char*)a_s;

    const float zd = a_d[(size_t)n * 6 + h];   // wave-uniform per head

    float ax = 0.f, ay = 0.f, az = 0.f, aw = 0.f, se = 0.f;

    if (deg <= 64) {
        int my3 = (l < deg) ? csr_src[nb + l] * 3 : 0;
        int i = 0;
        for (; i + 8 <= deg; i += 8) {
            unsigned s3[8]; float as[8]; uint2 xv[8];
            #pragma unroll
            for (int k = 0; k < 8; ++k) {
                s3[k] = (unsigned)__shfl(my3, i + k);
                as[k] = *(const float*)(asB + s3[k] * 8u + h4);
            }
            #pragma unroll
            for (int k = 0; k < 8; ++k)
                xv[k] = *(const uint2*)(xpB + s3[k] * 128u + lcb);
            #pragma unroll
            for (int k = 0; k < 8; ++k) {
                float z = as[k] + zd;
                z = z > 0.f ? z : 0.2f * z;
                float ev = __expf(z);
                ax = fmaf(ev, __uint_as_float(xv[k].x << 16), ax);
                ay = fmaf(ev, __uint_as_float(xv[k].x & 0xffff0000u), ay);
                az = fmaf(ev, __uint_as_float(xv[k].y << 16), az);
                aw = fmaf(ev, __uint_as_float(xv[k].y & 0xffff0000u), aw);
                se += ev;
            }
        }
        for (; i < deg; ++i) {
            unsigned s3 = (unsigned)__shfl(my3, i);
            float z  = *(const float*)(asB + s3 * 8u + h4) + zd;
            z = z > 0.f ? z : 0.2f * z;
            float ev = __expf(z);
            uint2 xv = *(const uint2*)(xpB + s3 * 128u + lcb);
            ax = fmaf(ev, __uint_as_float(xv.x << 16), ax);
            ay = fmaf(ev, __uint_as_float(xv.x & 0xffff0000u), ay);
            az = fmaf(ev, __uint_as_float(xv.y << 16), az);
            aw = fmaf(ev, __uint_as_float(xv.y & 0xffff0000u), aw);
            se += ev;
        }
    } else {
        int i = 0;
        for (; i + 4 <= deg; i += 4) {
            unsigned s3[4]; float as[4]; uint2 xv[4];
            #pragma unroll
            for (int k = 0; k < 4; ++k) {
                s3[k] = (unsigned)csr_src[nb + i + k] * 3u;
                as[k] = *(const float*)(asB + s3[k] * 8u + h4);
            }
            #pragma unroll
            for (int k = 0; k < 4; ++k)
                xv[k] = *(const uint2*)(xpB + s3[k] * 128u + lcb);
            #pragma unroll
            for (int k = 0; k < 4; ++k) {
                float z = as[k] + zd;
                z = z > 0.f ? z : 0.2f * z;
                float ev = __expf(z);
                ax = fmaf(ev, __uint_as_float(xv[k].x << 16), ax);
                ay = fmaf(ev, __uint_as_float(xv[k].x & 0xffff0000u), ay);
                az = fmaf(ev, __uint_as_float(xv[k].y << 16), az);
                aw = fmaf(ev, __uint_as_float(xv[k].y & 0xffff0000u), aw);
                se += ev;
            }
        }
        for (; i < deg; ++i) {
            unsigned s3 = (unsigned)csr_src[nb + i] * 3u;
            float z  = *(const float*)(asB + s3 * 8u + h4) + zd;
            z = z > 0.f ? z : 0.2f * z;
            float ev = __expf(z);
            uint2 xv = *(const uint2*)(xpB + s3 * 128u + lcb);
            ax = fmaf(ev, __uint_as_float(xv.x << 16), ax);
            ay = fmaf(ev, __uint_as_float(xv.x & 0xffff0000u), ay);
            az = fmaf(ev, __uint_as_float(xv.y << 16), az);
            aw = fmaf(ev, __uint_as_float(xv.y & 0xffff0000u), aw);
            se += ev;
        }
    }

    const float inv = 1.f / (se + 1e-16f);
    float v0 = (l < 48) ? ax * inv : 0.f;
    float v1 = (l < 48) ? ay * inv : 0.f;
    float v2 = (l < 48) ? az * inv : 0.f;
    float v3 = (l < 48) ? aw * inv : 0.f;

    #pragma unroll
    for (int d = 8; d <= 32; d <<= 1) {
        v0 += __shfl_down(v0, d);
        v1 += __shfl_down(v1, d);
        v2 += __shfl_down(v2, d);
        v3 += __shfl_down(v3, d);
    }

    if (l < 8) {
        float4 b4 = ((const float4*)bias)[l];
        const float sc = 1.0507009873554805f, al = 1.6732632423543772f;
        float m[4] = {v0 * (1.f / 6.f) + b4.x, v1 * (1.f / 6.f) + b4.y,
                      v2 * (1.f / 6.f) + b4.z, v3 * (1.f / 6.f) + b4.w};
        #pragma unroll
        for (int k = 0; k < 4; ++k)
            m[k] = m[k] > 0.f ? sc * m[k] : sc * al * (__expf(m[k]) - 1.f);
        ((float4*)out)[(size_t)n * 8 + l] = make_float4(m[0], m[1], m[2], m[3]);
    }
}

extern "C" void kernel_launch(void* const* d_in, const int* in_sizes, int n_in,
                              void* d_out, int out_size, void* d_ws, size_t ws_size,
                              hipStream_t stream)
{
    const float* x       = (const float*)d_in[0];
    const int*   ei      = (const int*)d_in[1];   // [2][E] int32
    const float* W       = (const float*)d_in[2];
    const float* att_src = (const float*)d_in[3];
    const float* att_dst = (const float*)d_in[4];
    const float* bias    = (const float*)d_in[5];
    float* out = (float*)d_out;

    const int N = in_sizes[0] / 128;
    const int E = in_sizes[1] / 2;
    const int NB = (N + 1023) / 1024;   // 98 <= 128 (k_off base-reduce capacity)

    char* ws = (char*)d_ws;
    size_t o = 0;
    auto take = [&](size_t bytes) { size_t r = o; o = (o + bytes + 255) & ~(size_t)255; return r; };
    unsigned short* xpb = (unsigned short*)(ws + take((size_t)N * 192 * 2));
    float* a_s     = (float*)(ws + take((size_t)N * 6 * 4));
    float* a_d     = (float*)(ws + take((size_t)N * 6 * 4));
    int*   off     = (int*)  (ws + take((size_t)(N + 1) * 4));
    int*   deg     = (int*)  (ws + take((size_t)N * 4));
    int*   rank    = (int*)  (ws + take((size_t)E * 4));
    int*   csr_src = (int*)  (ws + take((size_t)E * 4));
    int*   bsum    = (int*)  (ws + take((size_t)NB * 4));
    (void)ws_size; (void)n_in; (void)out_size;

    hipMemsetAsync(deg, 0, (size_t)N * 4, stream);

    k_gemm<<<(N + 63) / 64, 256, 0, stream>>>(x, W, att_src, att_dst,
                                              xpb, a_s, a_d, N);
    int eg = (E + 255) / 256;
    k_deg<<<eg, 256, 0, stream>>>(ei, deg, rank, E);
    k_bsum<<<NB, 256, 0, stream>>>(deg, bsum, N);
    k_off<<<NB, 256, 0, stream>>>(deg, bsum, off, N, NB);
    k_scat<<<eg, 256, 0, stream>>>(ei, off, rank, csr_src, E);
    k_agg<<<(N + 3) / 4, 256, 0, stream>>>(xpb, a_s, a_d, csr_src, off, bias, out, N);
}